// Round 4
// baseline (743.825 us; speedup 1.0000x reference)
//
#include <hip/hip_runtime.h>
#include <hip/hip_bf16.h>
#include <math.h>

// UHG InfoNCE: fused distance/similarity matrix + streaming row-logsumexp.
// N=8192, D=64 fp32. Mandatory traffic: ~537MB writes (sims+dists) -> ~86us floor.
//
// Analytic simplifications (all exact in fp32 semantics):
//  1. pos_sim cancels: per_row = -sims[i,0] + logsumexp_j(sims[i,j]).
//     (positive_indices unused.)
//  2. The reference clamp max(ratio, 1.0+1e-9) is max(ratio, 1.0f) in fp32.
//     ratio<1 for ~all pairs (inner ~ N(0,64) vs denom ~ 62) -> dist=0, sim=0
//     exactly. Fast path: classify by inner^2 vs 0.9999*max(|qq*kk|,eps);
//     borderline lanes take the exact div/clamp path (matches reference both
//     sides of the boundary; 1e-4 margin >> 1e-7 rounding).
//  3. All sims <= 0 and the reference row max is exactly 0 -> fix m=0,
//     accumulate S = sum(exp(sim)) directly (sim >= -few hundred, no overflow;
//     underflow only if an entire row is deep-negative, p ~ 1e-13).
//
// Structure: block = 32 rows x 4096 cols (column-split halves Kt re-staging
// and halves LDS-K bytes per FMA vs 16-row full-width blocks). Cross-block
// combine is S-only (one float per row per half).

#define NN 8192
#define DD 64

static constexpr float EPSV      = 1e-9f;
static constexpr float NEG_INV_T = -1.0f / 0.07f;   // sim = dist * NEG_INV_T

typedef const __attribute__((address_space(1))) unsigned int* gas_u32p;
typedef __attribute__((address_space(3))) unsigned int* las_u32p;

__device__ __forceinline__ void load_lds16(const void* g, void* l) {
    __builtin_amdgcn_global_load_lds((gas_u32p)g, (las_u32p)l, 16, 0, 0);
}

// ---------------------------------------------------------------------------
// Kernel 1: Kt[d][j] = K[j][d], with d==63 (timelike) negated.
// Folds the Minkowski signature into a plain dot-64 and makes the main
// kernel's LDS staging linear (global_load_lds-compatible).
// ---------------------------------------------------------------------------
__global__ __launch_bounds__(256) void uhg_transpose_negate(
    const float* __restrict__ K, float* __restrict__ Kt)
{
    __shared__ float T[64][65];
    const int tid = threadIdx.x;
    const int j0  = blockIdx.x * 64;
    {
        const int j = tid >> 2;           // 0..63 row of K within tile
        const int c = (tid & 3) * 16;     // dim chunk base
        const float* src = K + (size_t)(j0 + j) * DD + c;
        #pragma unroll
        for (int u = 0; u < 4; ++u) {
            const float4 v = *reinterpret_cast<const float4*>(src + 4 * u);
            T[j][c + 4*u + 0] = v.x;
            T[j][c + 4*u + 1] = v.y;
            T[j][c + 4*u + 2] = v.z;
            T[j][c + 4*u + 3] = v.w;
        }
    }
    __syncthreads();
    {
        const int d = tid >> 2;           // 0..63 output row (dim)
        const int c = (tid & 3) * 16;     // col chunk within tile
        const float sgn = (d == 63) ? -1.0f : 1.0f;
        float* dst = Kt + (size_t)d * NN + j0 + c;
        #pragma unroll
        for (int u = 0; u < 4; ++u) {
            float4 v;
            v.x = sgn * T[c + 4*u + 0][d];
            v.y = sgn * T[c + 4*u + 1][d];
            v.z = sgn * T[c + 4*u + 2][d];
            v.w = sgn * T[c + 4*u + 3][d];
            *reinterpret_cast<float4*>(dst + 4 * u) = v;
        }
    }
}

// ---------------------------------------------------------------------------
// Kernel 2: qq[i] = <q_i,q_i>_M, kk[j] = <k_j,k_j>_M (Minkowski self-inner).
// ---------------------------------------------------------------------------
__global__ __launch_bounds__(256) void uhg_qqkk(
    const float* __restrict__ Q, const float* __restrict__ K,
    float* __restrict__ qq, float* __restrict__ kk)
{
    const int i = blockIdx.x * 256 + threadIdx.x;   // 0 .. 2N-1
    const bool isQ = (i < NN);
    const int r = isQ ? i : (i - NN);
    const float* src = (isQ ? Q : K) + (size_t)r * DD;
    float acc = 0.0f;
    #pragma unroll
    for (int c = 0; c < 15; ++c) {
        const float4 v = *reinterpret_cast<const float4*>(src + 4 * c);
        acc += v.x*v.x + v.y*v.y + v.z*v.z + v.w*v.w;
    }
    const float4 v = *reinterpret_cast<const float4*>(src + 60);
    acc += v.x*v.x + v.y*v.y + v.z*v.z;
    acc -= v.w*v.w;                                  // timelike coordinate
    (isQ ? qq : kk)[r] = acc;
}

// ---------------------------------------------------------------------------
// Kernel 3: main fused kernel.
// Grid 512 blocks x 256 thr. Block (rblk, half) owns rows [32*rblk, +32) x
// cols [4096*half, +4096). Per 256-col tile: stage K' dim-major via
// global_load_lds; 8 rows x 4 cols per thread; clamp-classified epilogue;
// nontemporal coalesced stores; S-only row lse partials.
// ---------------------------------------------------------------------------
__global__ __launch_bounds__(256) void uhg_main(
    const float* __restrict__ Q, const float* __restrict__ Kt,
    const float* __restrict__ qq, const float* __restrict__ kk,
    float* __restrict__ out_sims, float* __restrict__ out_dist,
    float* __restrict__ Spart, float* __restrict__ sim0part)
{
    constexpr int TM = 32, TN = 256, NT = 4096 / TN;   // 16 tiles per block

    __shared__ float Qs[DD][36];          // dim-major Q tile (pad 36)
    __shared__ float Ks[DD][260];         // dim-major K' tile (pad 260)

    const int tid  = threadIdx.x;
    const int tx   = tid & 63;            // lane = column group
    const int ty   = tid >> 6;            // wave id 0..3 (uniform) = row group
    const int half = blockIdx.x & 1;      // column half
    const int row0 = (blockIdx.x >> 1) * TM;
    const int chalf = half * 4096;
    const int wrow = 8 * ty;              // wave's first row within tile

    // ---- stage Q tile (once): 32 rows x 64 dims, dim-major ----
    {
        const int r  = tid >> 3;          // 0..31
        const int dc = (tid & 7) * 8;     // 0..56
        const float* src = Q + (size_t)(row0 + r) * DD + dc;
        const float4 v0 = *reinterpret_cast<const float4*>(src);
        const float4 v1 = *reinterpret_cast<const float4*>(src + 4);
        Qs[dc + 0][r] = v0.x;  Qs[dc + 1][r] = v0.y;
        Qs[dc + 2][r] = v0.z;  Qs[dc + 3][r] = v0.w;
        Qs[dc + 4][r] = v1.x;  Qs[dc + 5][r] = v1.y;
        Qs[dc + 6][r] = v1.z;  Qs[dc + 7][r] = v1.w;
    }

    // per-thread row constants
    float rq[8];
    {
        const float4 a = *reinterpret_cast<const float4*>(qq + row0 + wrow);
        const float4 b = *reinterpret_cast<const float4*>(qq + row0 + wrow + 4);
        rq[0]=a.x; rq[1]=a.y; rq[2]=a.z; rq[3]=a.w;
        rq[4]=b.x; rq[5]=b.y; rq[6]=b.z; rq[7]=b.w;
    }

    float s[8]     = {0,0,0,0,0,0,0,0};   // S = sum(exp(sim)), m fixed at 0
    float sim0r[8] = {0,0,0,0,0,0,0,0};   // col-0 sim (lane tx==0, half==0)

    // per-row output bases (rows wave-uniform; +tx gives the lane col)
    float* ps[8];
    float* pd[8];
    #pragma unroll
    for (int rr = 0; rr < 8; ++rr) {
        const size_t rowoff = (size_t)(row0 + wrow + rr) * NN + chalf + tx;
        ps[rr] = out_sims + rowoff;
        pd[rr] = out_dist + rowoff;
    }

    for (int t = 0; t < NT; ++t) {
        const int c0 = t * TN;            // within this block's column half
        __syncthreads();                  // protect Ks from previous readers

        // ---- stage K' tile: wave w loads dims 16w..16w+15, 1KB rows ----
        {
            const int dbase = ty * 16;
            #pragma unroll
            for (int j = 0; j < 16; ++j) {
                const int d = dbase + j;
                load_lds16(Kt + (size_t)d * NN + chalf + c0 + 4 * tx, &Ks[d][0]);
            }
        }
        __syncthreads();

        // ---- dot-64: 8 rows x 4 cols per thread ----
        float acc[8][4] = {};
        #pragma unroll 4
        for (int d = 0; d < DD; ++d) {
            const float4 qv0 = *reinterpret_cast<const float4*>(&Qs[d][wrow]);
            const float4 qv1 = *reinterpret_cast<const float4*>(&Qs[d][wrow + 4]);
            const float qa[8] = {qv0.x, qv0.y, qv0.z, qv0.w,
                                 qv1.x, qv1.y, qv1.z, qv1.w};
            float kv[4];
            kv[0] = Ks[d][tx];
            kv[1] = Ks[d][tx + 64];
            kv[2] = Ks[d][tx + 128];
            kv[3] = Ks[d][tx + 192];
            #pragma unroll
            for (int rr = 0; rr < 8; ++rr)
                #pragma unroll
                for (int i = 0; i < 4; ++i)
                    acc[rr][i] = fmaf(qa[rr], kv[i], acc[rr][i]);
        }

        // ---- epilogue: clamp-classified distance/sim, stores, S update ----
        float rk[4];
        rk[0] = kk[chalf + c0 + tx];
        rk[1] = kk[chalf + c0 + tx + 64];
        rk[2] = kk[chalf + c0 + tx + 128];
        rk[3] = kk[chalf + c0 + tx + 192];

        #pragma unroll
        for (int rr = 0; rr < 8; ++rr) {
            #pragma unroll
            for (int i = 0; i < 4; ++i) {
                const float inner = acc[rr][i];
                const float dd = fmaxf(fabsf(rq[rr] * rk[i]), EPSV);
                float dist = 0.0f, sim = 0.0f, e = 1.0f;
                if (inner * inner > dd * 0.9999f) {   // rare: ratio may be >= 1
                    const float ratio = fmaxf(fabsf(inner) / sqrtf(dd), 1.0f);
                    dist = __logf(ratio + sqrtf(fmaf(ratio, ratio, -1.0f)));
                    sim  = dist * NEG_INV_T;
                    e    = __expf(sim);
                }
                __builtin_nontemporal_store(dist, pd[rr] + c0 + 64 * i);
                __builtin_nontemporal_store(sim,  ps[rr] + c0 + 64 * i);
                if (half == 0 && t == 0 && i == 0 && tx == 0) sim0r[rr] = sim;
                s[rr] += e;
            }
        }
    }

    // ---- reduce S across the 64 lanes of each row (butterfly) ----
    #pragma unroll
    for (int rr = 0; rr < 8; ++rr) {
        float v = s[rr];
        #pragma unroll
        for (int mask = 32; mask > 0; mask >>= 1)
            v += __shfl_xor(v, mask, 64);
        s[rr] = v;
    }
    if (tx == 0) {
        #pragma unroll
        for (int rr = 0; rr < 8; ++rr) {
            const int row = row0 + wrow + rr;
            Spart[half * NN + row] = s[rr];
            if (half == 0) sim0part[row] = sim0r[rr];
        }
    }
}

// ---------------------------------------------------------------------------
// Kernel 4: loss = sum_i(-sim0_i + log(S0_i + S1_i)) / N. Single block.
// ---------------------------------------------------------------------------
__global__ __launch_bounds__(256) void uhg_finalize(
    const float* __restrict__ Spart, const float* __restrict__ sim0part,
    float* __restrict__ out)
{
    __shared__ float red[256];
    const int tid = threadIdx.x;
    float a = 0.0f;
    for (int r = tid; r < NN; r += 256) {
        const float S = Spart[r] + Spart[NN + r];
        a += -sim0part[r] + logf(S);
    }
    red[tid] = a;
    __syncthreads();
    for (int off = 128; off > 0; off >>= 1) {
        if (tid < off) red[tid] += red[tid + off];
        __syncthreads();
    }
    if (tid == 0) out[0] = red[0] / (float)NN;
}

// ---------------------------------------------------------------------------
extern "C" void kernel_launch(void* const* d_in, const int* in_sizes, int n_in,
                              void* d_out, int out_size, void* d_ws, size_t ws_size,
                              hipStream_t stream)
{
    const float* Q = (const float*)d_in[0];
    const float* K = (const float*)d_in[1];
    // d_in[2] (positive_indices) cancels analytically -> unused.

    float* out      = (float*)d_out;
    float* out_sims = out + 1;
    float* out_dist = out + 1 + (size_t)NN * NN;

    float* w        = (float*)d_ws;       // needs ~2.2MB of ws
    float* Kt       = w;                  // 64*8192 = 524288 floats
    float* qq       = w + 524288;         // 8192
    float* kk       = w + 532480;         // 8192
    float* Spart    = w + 540672;         // 2*8192
    float* sim0part = w + 557056;         // 8192

    uhg_transpose_negate<<<NN / 64, 256, 0, stream>>>(K, Kt);
    uhg_qqkk<<<2 * NN / 256, 256, 0, stream>>>(Q, K, qq, kk);
    uhg_main<<<512, 256, 0, stream>>>(Q, Kt, qq, kk, out_sims, out_dist,
                                      Spart, sim0part);
    uhg_finalize<<<1, 256, 0, stream>>>(Spart, sim0part, out);
}